// Round 5
// baseline (235.276 us; speedup 1.0000x reference)
//
#include <hip/hip_runtime.h>

#define NN 50000
#define NE 800000
#define H  64
#define SCAN_B 196  // ceil(NN/256); 196*256 = 50176

typedef __attribute__((ext_vector_type(8))) short bf16x8;
typedef __attribute__((ext_vector_type(4))) float f32x4;

__device__ __forceinline__ unsigned short f2bf(float f) {
  unsigned int u = __builtin_bit_cast(unsigned int, f);
  u += 0x7FFFu + ((u >> 16) & 1u);  // RNE
  return (unsigned short)(u >> 16);
}
__device__ __forceinline__ float bf2f(unsigned short u) {
  unsigned int v = ((unsigned int)u) << 16;
  return __builtin_bit_cast(float, v);
}

// ---------- count in-degree (dst) ----------
__global__ __launch_bounds__(256) void k_zero(int* __restrict__ cnt) {
  int i = blockIdx.x * 256 + threadIdx.x;
  if (i < NN) cnt[i] = 0;
}

__global__ __launch_bounds__(256) void k_hist(const int* __restrict__ ei,
                                              int* __restrict__ cnt) {
  int e = blockIdx.x * 256 + threadIdx.x;
  atomicAdd(&cnt[ei[NE + e]], 1);
}

// ---------- hierarchical exclusive scan ----------
__global__ __launch_bounds__(256) void k_scan_local(const int* __restrict__ cnt,
                                                    int* __restrict__ loc,
                                                    int* __restrict__ bsum) {
  __shared__ int sh[256];
  const int t = threadIdx.x;
  const int i = blockIdx.x * 256 + t;
  const int v = (i < NN) ? cnt[i] : 0;
  sh[t] = v;
  __syncthreads();
  int val = v;
#pragma unroll
  for (int off = 1; off < 256; off <<= 1) {
    int o = (t >= off) ? sh[t - off] : 0;
    __syncthreads();
    val += o;
    sh[t] = val;
    __syncthreads();
  }
  if (i < NN) loc[i] = val - v;  // exclusive
  if (t == 255) bsum[blockIdx.x] = val;
}

__global__ __launch_bounds__(256) void k_scan_bsum(const int* __restrict__ bsum,
                                                   int* __restrict__ boff) {
  __shared__ int sh[256];
  const int t = threadIdx.x;
  const int v = (t < SCAN_B) ? bsum[t] : 0;
  sh[t] = v;
  __syncthreads();
  int val = v;
#pragma unroll
  for (int off = 1; off < 256; off <<= 1) {
    int o = (t >= off) ? sh[t - off] : 0;
    __syncthreads();
    val += o;
    sh[t] = val;
    __syncthreads();
  }
  if (t < SCAN_B) boff[t] = val - v;  // exclusive
}

__global__ __launch_bounds__(256) void k_scan_add(const int* __restrict__ loc,
                                                  const int* __restrict__ boff,
                                                  const int* __restrict__ cnt,
                                                  int* __restrict__ rowptr,
                                                  int* __restrict__ cursor,
                                                  float* __restrict__ dinv) {
  const int i = blockIdx.x * 256 + threadIdx.x;
  if (i < NN) {
    const int r = loc[i] + boff[blockIdx.x];
    rowptr[i] = r;
    cursor[i] = r;
    dinv[i] = rsqrtf((float)(cnt[i] + 1));  // +1 self-loop
  }
  if (i == 0) rowptr[NN] = NE;
}

// ---------- node encoder + h0@W_gcn; htb = bf16(ht * dinv[n]) ----------
__global__ __launch_bounds__(256) void k_node(
    const float* __restrict__ x, const float* __restrict__ W_ne,
    const float* __restrict__ b_ne, const float* __restrict__ W_gcn,
    const float* __restrict__ dinv, unsigned short* __restrict__ htb) {
  __shared__ float sh[4][H];
  const int lane = threadIdx.x & 63;
  const int wv   = threadIdx.x >> 6;
  const int n    = blockIdx.x * 4 + wv;

  float acc = b_ne[lane];
#pragma unroll
  for (int k = 0; k < 5; ++k) acc = fmaf(x[n * 5 + k], W_ne[k * H + lane], acc);
  acc = fmaxf(acc, 0.0f);
  sh[wv][lane] = acc;
  __syncthreads();

  float hv = 0.0f;
#pragma unroll 8
  for (int k = 0; k < H; ++k) hv = fmaf(sh[wv][k], W_gcn[k * H + lane], hv);

  htb[(size_t)n * H + lane] = f2bf(hv * dinv[n]);
}

// ---------- reorder: csr_src grouped by dst ----------
__global__ __launch_bounds__(256) void k_reorder(const int* __restrict__ ei,
                                                 int* __restrict__ cursor,
                                                 int* __restrict__ csr_src) {
  int e = blockIdx.x * 256 + threadIdx.x;
  int s = ei[e], d = ei[NE + e];
  int pos = atomicAdd(&cursor[d], 1);
  csr_src[pos] = s;
}

// ---------- gather: hgb[d] = bf16(dinv[d]*(htb[d] + sum htb[src]) + b_gcn) ----------
__global__ __launch_bounds__(256) void k_gather(
    const int* __restrict__ rowptr, const int* __restrict__ csr_src,
    const unsigned short* __restrict__ htb, const float* __restrict__ dinv,
    const float* __restrict__ b_gcn, unsigned short* __restrict__ hgb) {
  const int lane = threadIdx.x & 63;
  const int wv   = threadIdx.x >> 6;
  const int n    = blockIdx.x * 4 + wv;  // NN % 4 == 0
  const int beg = rowptr[n], end = rowptr[n + 1];

  float sum = bf2f(htb[(size_t)n * H + lane]);  // self-loop term
  int i = beg;
#pragma unroll 1
  for (; i + 4 <= end; i += 4) {
    const int s0 = csr_src[i], s1 = csr_src[i + 1];
    const int s2 = csr_src[i + 2], s3 = csr_src[i + 3];
    const float v0 = bf2f(htb[(size_t)s0 * H + lane]);
    const float v1 = bf2f(htb[(size_t)s1 * H + lane]);
    const float v2 = bf2f(htb[(size_t)s2 * H + lane]);
    const float v3 = bf2f(htb[(size_t)s3 * H + lane]);
    sum += (v0 + v1) + (v2 + v3);
  }
#pragma unroll 1
  for (; i < end; ++i) sum += bf2f(htb[(size_t)csr_src[i] * H + lane]);

  hgb[(size_t)n * H + lane] = f2bf(fmaf(dinv[n], sum, b_gcn[lane]));
}

// ---------- prep: W1 (f32 [192][64]) -> W1t (bf16 [64][192]) ----------
__global__ __launch_bounds__(256) void k_prep_w1t(const float* __restrict__ W1,
                                                  unsigned short* __restrict__ W1t) {
  const int t = blockIdx.x * 256 + threadIdx.x;  // 48*256 = 12288 = 64*192
  const int h = t / 192, k = t % 192;
  W1t[h * 192 + k] = f2bf(W1[k * H + h]);
}

// ---------- MFMA edge MLP (swapped operands, W1 in registers, no LDS) ----------
__global__ __launch_bounds__(256) void k_mlp_mfma(
    const int* __restrict__ ei, const float* __restrict__ eattr,
    const unsigned short* __restrict__ hgb, const unsigned short* __restrict__ W1t,
    const float* __restrict__ W_ee, const float* __restrict__ b_ee,
    const float* __restrict__ b1, const float* __restrict__ W2,
    const float* __restrict__ b2, float* __restrict__ out) {
  const int lane = threadIdx.x & 63;
  const int wv   = threadIdx.x >> 6;
  const int l15  = lane & 15;
  const int l4   = lane >> 4;

  // ---- persistent: W1^T fragments (A-operand), row = h = nt*16+l15, k = c*32+l4*8+j
  bf16x8 wf[4][6];
#pragma unroll
  for (int nt = 0; nt < 4; ++nt)
#pragma unroll
    for (int c = 0; c < 6; ++c)
      wf[nt][c] = *(const bf16x8*)(W1t + (nt * 16 + l15) * 192 + c * 32 + l4 * 8);

  // per-lane h-slice constants: h = nt*16 + l4*4 + r (D-layout rows)
  float b1v[4][4], w2v[4][4];
#pragma unroll
  for (int nt = 0; nt < 4; ++nt)
#pragma unroll
    for (int r = 0; r < 4; ++r) {
      b1v[nt][r] = b1[nt * 16 + l4 * 4 + r];
      w2v[nt][r] = W2[nt * 16 + l4 * 4 + r];
    }
  float wee[16], bee[16];
#pragma unroll
  for (int j = 0; j < 8; ++j) {
    wee[j]     = W_ee[l4 * 8 + j];      bee[j]     = b_ee[l4 * 8 + j];
    wee[8 + j] = W_ee[32 + l4 * 8 + j]; bee[8 + j] = b_ee[32 + l4 * 8 + j];
  }
  const float bias2 = b2[0];

  // ---- edge indices for all 4 tiles (prefetched) ----
  const int base = (blockIdx.x * 16 + wv * 4) * 16 + l15;
  int si[4], di[4];
  float ea[4];
#pragma unroll
  for (int t = 0; t < 4; ++t) {
    si[t] = ei[base + t * 16];
    di[t] = ei[NE + base + t * 16];
    ea[t] = eattr[base + t * 16];
  }

  // ---- double-buffered edge fragments (B-operand): col = l15, k = l4*8+j ----
  bf16x8 fs0[2], fs1[2], fd0[2], fd1[2];
  fs0[0] = *(const bf16x8*)(hgb + (size_t)si[0] * H + l4 * 8);
  fs1[0] = *(const bf16x8*)(hgb + (size_t)si[0] * H + 32 + l4 * 8);
  fd0[0] = *(const bf16x8*)(hgb + (size_t)di[0] * H + l4 * 8);
  fd1[0] = *(const bf16x8*)(hgb + (size_t)di[0] * H + 32 + l4 * 8);

#pragma unroll
  for (int t = 0; t < 4; ++t) {
    const int cur = t & 1, nxt = cur ^ 1;
    if (t < 3) {  // prefetch next tile's gathers (overlaps this tile's MFMAs)
      fs0[nxt] = *(const bf16x8*)(hgb + (size_t)si[t + 1] * H + l4 * 8);
      fs1[nxt] = *(const bf16x8*)(hgb + (size_t)si[t + 1] * H + 32 + l4 * 8);
      fd0[nxt] = *(const bf16x8*)(hgb + (size_t)di[t + 1] * H + l4 * 8);
      fd1[nxt] = *(const bf16x8*)(hgb + (size_t)di[t + 1] * H + 32 + l4 * 8);
    }

    // edge-feature block fragments (VALU, overlaps gather latency)
    bf16x8 ae0, ae1;
#pragma unroll
    for (int j = 0; j < 8; ++j) {
      ae0[j] = (short)f2bf(fmaxf(fmaf(ea[t], wee[j], bee[j]), 0.0f));
      ae1[j] = (short)f2bf(fmaxf(fmaf(ea[t], wee[8 + j], bee[8 + j]), 0.0f));
    }

    f32x4 acc[4];
#pragma unroll
    for (int nt = 0; nt < 4; ++nt) {
      acc[nt][0] = b1v[nt][0]; acc[nt][1] = b1v[nt][1];
      acc[nt][2] = b1v[nt][2]; acc[nt][3] = b1v[nt][3];
    }
#pragma unroll
    for (int nt = 0; nt < 4; ++nt) {
      acc[nt] = __builtin_amdgcn_mfma_f32_16x16x32_bf16(wf[nt][0], fs0[cur], acc[nt], 0, 0, 0);
      acc[nt] = __builtin_amdgcn_mfma_f32_16x16x32_bf16(wf[nt][1], fs1[cur], acc[nt], 0, 0, 0);
      acc[nt] = __builtin_amdgcn_mfma_f32_16x16x32_bf16(wf[nt][2], fd0[cur], acc[nt], 0, 0, 0);
      acc[nt] = __builtin_amdgcn_mfma_f32_16x16x32_bf16(wf[nt][3], fd1[cur], acc[nt], 0, 0, 0);
      acc[nt] = __builtin_amdgcn_mfma_f32_16x16x32_bf16(wf[nt][4], ae0,      acc[nt], 0, 0, 0);
      acc[nt] = __builtin_amdgcn_mfma_f32_16x16x32_bf16(wf[nt][5], ae1,      acc[nt], 0, 0, 0);
    }

    // layer 2: lane-local over its 16 h-values, then 2-step cross-l4 reduce
    float p = 0.0f;
#pragma unroll
    for (int nt = 0; nt < 4; ++nt)
#pragma unroll
      for (int r = 0; r < 4; ++r)
        p = fmaf(fmaxf(acc[nt][r], 0.0f), w2v[nt][r], p);
    p += __shfl_xor(p, 16);
    p += __shfl_xor(p, 32);
    if (lane < 16) out[base + t * 16] = p + bias2;
  }
}

extern "C" void kernel_launch(void* const* d_in, const int* in_sizes, int n_in,
                              void* d_out, int out_size, void* d_ws, size_t ws_size,
                              hipStream_t stream) {
  const float* x     = (const float*)d_in[0];
  const int*   ei    = (const int*)d_in[1];
  const float* eattr = (const float*)d_in[2];
  const float* W_ne  = (const float*)d_in[3];
  const float* b_ne  = (const float*)d_in[4];
  const float* W_ee  = (const float*)d_in[5];
  const float* b_ee  = (const float*)d_in[6];
  const float* W_gcn = (const float*)d_in[7];
  const float* b_gcn = (const float*)d_in[8];
  const float* W1    = (const float*)d_in[9];
  const float* b1    = (const float*)d_in[10];
  const float* W2    = (const float*)d_in[11];
  const float* b2    = (const float*)d_in[12];
  float* out = (float*)d_out;

  char* ws = (char*)d_ws;
  unsigned short* htb = (unsigned short*)ws;                      // NN*H bf16
  unsigned short* hgb = htb + (size_t)NN * H;                     // NN*H bf16
  int*   cnt     = (int*)(hgb + (size_t)NN * H);                  // NN
  int*   rowptr  = cnt + NN;                                      // NN+1
  int*   cursor  = rowptr + NN + 1;                               // NN
  float* dinv    = (float*)(cursor + NN);                         // NN
  int*   csr_src = (int*)(dinv + NN);                             // NE
  unsigned short* W1t = (unsigned short*)(csr_src + NE);          // 64*192
  int*   loc     = (int*)(W1t + 64 * 192);                        // NN
  int*   bsum    = loc + NN;                                      // SCAN_B
  int*   boff    = bsum + SCAN_B;                                 // SCAN_B

  k_zero<<<SCAN_B, 256, 0, stream>>>(cnt);
  k_hist<<<NE / 256, 256, 0, stream>>>(ei, cnt);
  k_scan_local<<<SCAN_B, 256, 0, stream>>>(cnt, loc, bsum);
  k_scan_bsum<<<1, 256, 0, stream>>>(bsum, boff);
  k_scan_add<<<SCAN_B, 256, 0, stream>>>(loc, boff, cnt, rowptr, cursor, dinv);
  k_prep_w1t<<<48, 256, 0, stream>>>(W1, W1t);
  k_node<<<NN / 4, 256, 0, stream>>>(x, W_ne, b_ne, W_gcn, dinv, htb);
  k_reorder<<<NE / 256, 256, 0, stream>>>(ei, cursor, csr_src);
  k_gather<<<NN / 4, 256, 0, stream>>>(rowptr, csr_src, htb, dinv, b_gcn, hgb);
  k_mlp_mfma<<<NE / 256, 256, 0, stream>>>(ei, eattr, hgb, W1t, W_ee, b_ee, b1, W2, b2, out);
}